// Round 11
// baseline (1823.252 us; speedup 1.0000x reference)
//
#include <hip/hip_runtime.h>
#include <hip/hip_cooperative_groups.h>

namespace cg = cooperative_groups;

#define NPTS 4096
#define NB   4
#define CH   512
#define TOT  (NB * NPTS)   // 16384
#define KNN  5

typedef _Float16 half8_t __attribute__((ext_vector_type(8)));
typedef float    f32x4   __attribute__((ext_vector_type(4)));

typedef __attribute__((address_space(1))) const void gas_t;
typedef __attribute__((address_space(3))) void las_t;
#define GLOAD16(g, l) __builtin_amdgcn_global_load_lds((gas_t*)(g), (las_t*)(l), 16, 0, 0)

// ---------------- prep: transpose (blocks 0..8191) + weight convert (8192..9855) ----------------
__global__ __launch_bounds__(256) void prep_kernel(const float* __restrict__ x,
                                                   _Float16* __restrict__ xt,
                                                   const float* __restrict__ s0,
                                                   const float* __restrict__ s1,
                                                   const float* __restrict__ s2,
                                                   const float* __restrict__ s3,
                                                   _Float16* __restrict__ d0,
                                                   _Float16* __restrict__ d1,
                                                   _Float16* __restrict__ d2,
                                                   _Float16* __restrict__ d3) {
    __shared__ float tile[32][33];
    const int blk = blockIdx.x;
    if (blk < 8192) {
        int b  = blk >> 11;
        int by = (blk >> 7) & 15;
        int bx = blk & 127;
        int n0 = bx * 32, c0 = by * 32;
        int tx = threadIdx.x & 31, ty = threadIdx.x >> 5;
        const float* xp = x + ((size_t)b * CH + c0) * NPTS + n0;
#pragma unroll
        for (int i = 0; i < 32; i += 8)
            tile[ty + i][tx] = xp[(size_t)(ty + i) * NPTS + tx];   // tile[chan][n]
        __syncthreads();
        int t2 = threadIdx.x & 15, rr = threadIdx.x >> 4;
#pragma unroll
        for (int i = 0; i < 32; i += 16) {
            int nn = rr + i;
            union { unsigned u; _Float16 h[2]; } o;
            o.h[0] = (_Float16)tile[2 * t2][nn];
            o.h[1] = (_Float16)tile[2 * t2 + 1][nn];
            *(unsigned*)(xt + ((size_t)b * NPTS + n0 + nn) * CH + c0 + 2 * t2) = o.u;
        }
    } else {
        const int cb = blk - 8192;   // 0..1663
        const float* s; _Float16* d; int i;
        if (cb < 512)       { s = s0; d = d0; i = cb; }
        else if (cb < 1024) { s = s1; d = d1; i = cb - 512; }
        else if (cb < 1536) { s = s2; d = d2; i = cb - 1024; }
        else                { s = s3; d = d3; i = cb - 1536; }
        int q = i * 256 + threadIdx.x;
        float4 v = ((const float4*)s)[q];
        union { unsigned long long u; _Float16 h[4]; } o;
        o.h[0] = (_Float16)v.x; o.h[1] = (_Float16)v.y;
        o.h[2] = (_Float16)v.z; o.h[3] = (_Float16)v.w;
        *(unsigned long long*)(d + (size_t)q * 4) = o.u;
    }
}

// ---------------- KNN: FROZEN at v2: 16 waves, scalar LDS reads ----------------
__global__ __launch_bounds__(1024) void knn_kernel(const float* __restrict__ pos,
                                                   int* __restrict__ idxOut) {
#pragma clang fp contract(off)
    __shared__ float cx[NPTS];
    __shared__ float cy[NPTS];
    __shared__ float d2s[NPTS];
    __shared__ float cd[16][64][KNN];
    __shared__ int   ci[16][64][KNN];
    __shared__ float cd2[4][64][KNN];
    __shared__ int   ci2[4][64][KNN];
    const int b  = blockIdx.x >> 6;
    const int q0 = (blockIdx.x & 63) << 6;
    const int wv = threadIdx.x >> 6;
    const int ln = threadIdx.x & 63;
    const int n  = q0 + ln;
    const float2* P = (const float2*)(pos + (size_t)b * NPTS * 2);
    for (int m = threadIdx.x; m < NPTS; m += 1024) {
        float2 c = P[m];
        cx[m] = c.x; cy[m] = c.y;
        float xx = c.x * c.x;
        float yy = c.y * c.y;
        d2s[m] = xx + yy;
    }
    __syncthreads();
    const float xq = cx[n], yq = cy[n], d2q = d2s[n];
    float bd0 = 3.4e38f, bd1 = 3.4e38f, bd2 = 3.4e38f, bd3 = 3.4e38f, bd4 = 3.4e38f;
    int   bi0 = 0, bi1 = 0, bi2 = 0, bi3 = 0, bi4 = 0;
    const int m0 = wv << 8, m1 = m0 + 256;
    for (int m = m0; m < m1; m += 4) {
        float dist[4];
#pragma unroll
        for (int u = 0; u < 4; ++u) {
            float px  = xq * cx[m + u];
            float dot = __builtin_fmaf(yq, cy[m + u], px);
            float s   = d2q + d2s[m + u];
            float t2  = 2.0f * dot;
            dist[u] = s - t2;
        }
        float mn = fminf(fminf(dist[0], dist[1]), fminf(dist[2], dist[3]));
        if (mn < bd4) {
#pragma unroll
            for (int u = 0; u < 4; ++u) {
                float d = dist[u];
                if (d < bd4) {
                    bd4 = d; bi4 = m + u;
                    if (bd4 < bd3) { float t = bd3; bd3 = bd4; bd4 = t; int v = bi3; bi3 = bi4; bi4 = v; }
                    if (bd3 < bd2) { float t = bd2; bd2 = bd3; bd3 = t; int v = bi2; bi2 = bi3; bi3 = v; }
                    if (bd2 < bd1) { float t = bd1; bd1 = bd2; bd2 = t; int v = bi1; bi1 = bi2; bi2 = v; }
                    if (bd1 < bd0) { float t = bd0; bd0 = bd1; bd1 = t; int v = bi0; bi0 = bi1; bi1 = v; }
                }
            }
        }
    }
    cd[wv][ln][0] = bd0; cd[wv][ln][1] = bd1; cd[wv][ln][2] = bd2; cd[wv][ln][3] = bd3; cd[wv][ln][4] = bd4;
    ci[wv][ln][0] = bi0; ci[wv][ln][1] = bi1; ci[wv][ln][2] = bi2; ci[wv][ln][3] = bi3; ci[wv][ln][4] = bi4;
    __syncthreads();
    if (wv < 4) {
        float md0 = 3.4e38f, md1 = 3.4e38f, md2 = 3.4e38f, md3 = 3.4e38f, md4 = 3.4e38f;
        int   mi0 = 0, mi1 = 0, mi2 = 0, mi3 = 0, mi4 = 0;
#pragma unroll
        for (int w = 4 * wv; w < 4 * wv + 4; ++w) {
#pragma unroll
            for (int j = 0; j < KNN; ++j) {
                float d = cd[w][ln][j];
                int  id = ci[w][ln][j];
                if (d < md4) {
                    md4 = d; mi4 = id;
                    if (md4 < md3) { float t = md3; md3 = md4; md4 = t; int v = mi3; mi3 = mi4; mi4 = v; }
                    if (md3 < md2) { float t = md2; md2 = md3; md3 = t; int v = mi2; mi2 = mi3; mi3 = v; }
                    if (md2 < md1) { float t = md1; md1 = md2; md2 = t; int v = mi1; mi1 = mi2; mi2 = v; }
                    if (md1 < md0) { float t = md0; md0 = md1; md1 = t; int v = mi0; mi0 = mi1; mi1 = v; }
                }
            }
        }
        cd2[wv][ln][0] = md0; cd2[wv][ln][1] = md1; cd2[wv][ln][2] = md2; cd2[wv][ln][3] = md3; cd2[wv][ln][4] = md4;
        ci2[wv][ln][0] = mi0; ci2[wv][ln][1] = mi1; ci2[wv][ln][2] = mi2; ci2[wv][ln][3] = mi3; ci2[wv][ln][4] = mi4;
    }
    __syncthreads();
    if (wv == 0) {
        float md0 = 3.4e38f, md1 = 3.4e38f, md2 = 3.4e38f, md3 = 3.4e38f, md4 = 3.4e38f;
        int   mi0 = 0, mi1 = 0, mi2 = 0, mi3 = 0, mi4 = 0;
#pragma unroll
        for (int w = 0; w < 4; ++w) {
#pragma unroll
            for (int j = 0; j < KNN; ++j) {
                float d = cd2[w][ln][j];
                int  id = ci2[w][ln][j];
                if (d < md4) {
                    md4 = d; mi4 = id;
                    if (md4 < md3) { float t = md3; md3 = md4; md4 = t; int v = mi3; mi3 = mi4; mi4 = v; }
                    if (md3 < md2) { float t = md2; md2 = md3; md3 = t; int v = mi2; mi2 = mi3; mi3 = v; }
                    if (md2 < md1) { float t = md1; md1 = md2; md2 = t; int v = mi1; mi1 = mi2; mi2 = v; }
                    if (md1 < md0) { float t = md0; md0 = md1; md1 = t; int v = mi0; mi0 = mi1; mi1 = v; }
                }
            }
        }
        int* op = idxOut + ((size_t)b * NPTS + n) * KNN;
        op[0] = mi0; op[1] = mi1; op[2] = mi2; op[3] = mi3; op[4] = mi4;
    }
}

// ---------------- feat body (shared by standalone + pipe) ----------------
__device__ __forceinline__ void feat_body(const _Float16* __restrict__ xt,
                                          const int* __restrict__ idx,
                                          _Float16* __restrict__ feat,
                                          int p, int base, int ch0) {
    const int* ip = idx + (size_t)p * KNN;
    const _Float16* xr = xt + (size_t)p * CH + ch0;
    const _Float16* g0 = xt + (size_t)(base + ip[0]) * CH + ch0;
    const _Float16* g1 = xt + (size_t)(base + ip[1]) * CH + ch0;
    const _Float16* g2 = xt + (size_t)(base + ip[2]) * CH + ch0;
    const _Float16* g3 = xt + (size_t)(base + ip[3]) * CH + ch0;
    const _Float16* g4 = xt + (size_t)(base + ip[4]) * CH + ch0;
    union u16x8 { uint4 v; _Float16 h[8]; };
    u16x8 ux, u0, u1, u2, u3, u4;
    ux.v = *(const uint4*)xr;
    u0.v = *(const uint4*)g0;
    u1.v = *(const uint4*)g1;
    u2.v = *(const uint4*)g2;
    u3.v = *(const uint4*)g3;
    u4.v = *(const uint4*)g4;
    u16x8 oa, ob;
#pragma unroll
    for (int j2 = 0; j2 < 8; ++j2) {
        float xv = (float)ux.h[j2];
        float mr = fmaxf(fmaxf(fmaxf((float)u0.h[j2], (float)u1.h[j2]),
                               fmaxf((float)u2.h[j2], (float)u3.h[j2])), (float)u4.h[j2]) - xv;
        if (j2 < 4) {
            oa.h[2 * j2]     = ux.h[j2];
            oa.h[2 * j2 + 1] = (_Float16)mr;
        } else {
            ob.h[2 * (j2 - 4)]     = ux.h[j2];
            ob.h[2 * (j2 - 4) + 1] = (_Float16)mr;
        }
    }
    _Float16* op = feat + (size_t)p * 2 * CH + 2 * ch0;
    *(uint4*)(op)     = oa.v;
    *(uint4*)(op + 8) = ob.v;
}

// ---------------- standalone feat (fallback path, r9-identical behavior) ----------------
__global__ __launch_bounds__(256) void feat_kernel(const _Float16* __restrict__ xt,
                                                   const int* __restrict__ idx,
                                                   _Float16* __restrict__ feat,
                                                   float* __restrict__ pzero) {
    if (blockIdx.x == 0) {
        float4 z = {0.f, 0.f, 0.f, 0.f};
        ((float4*)pzero)[threadIdx.x] = z;
    }
    const int blk   = blockIdx.x;
    const int batch = (blk & 7) >> 1;
    const int halfp = blk & 1;
    const int j     = blk >> 3;
    const int p     = batch * NPTS + halfp * 2048 + j * 4 + (threadIdx.x >> 6);
    feat_body(xt, idx, feat, p, batch * NPTS, (threadIdx.x & 63) * 8);
}

// ---------------- GEMM body (r9-identical inner code) ----------------
template <bool RELU, bool STATS>
__device__ __forceinline__ void gemm_body(const _Float16* __restrict__ A,
                                          const _Float16* __restrict__ B,
                                          const float* __restrict__ bias,
                                          float* __restrict__ C, int N, int K,
                                          float* __restrict__ psum, float* __restrict__ psq,
                                          _Float16* As, _Float16* Bs,
                                          int bm, int bn, int tid) {
    const int wv = tid >> 6, ln = tid & 63;
    const int wm = (wv >> 1) * 64, wn = (wv & 1) * 64;
    const int lq = ln >> 4, lc = ln & 15;
    const int srow = wv * 8 + (ln >> 3);
    const int scol = (ln & 7) * 8;
    const _Float16* Ag = A + (size_t)(bm + srow) * K + scol;
    const _Float16* Bg = B + (size_t)(bn + srow) * K + scol;
    _Float16* AsW = As + wv * 512;
    _Float16* BsW = Bs + wv * 512;

    f32x4 zero = {0.0f, 0.0f, 0.0f, 0.0f};
    f32x4 acc[4][4];
#pragma unroll
    for (int i = 0; i < 4; ++i)
#pragma unroll
        for (int j = 0; j < 4; ++j) acc[i][j] = zero;

    for (int k0 = 0; k0 < K; k0 += 64) {
        __syncthreads();
#pragma unroll
        for (int c = 0; c < 4; ++c) {
            GLOAD16(Ag + (size_t)c * 32 * K + k0, AsW + c * 2048);
            GLOAD16(Bg + (size_t)c * 32 * K + k0, BsW + c * 2048);
        }
        __syncthreads();
#pragma unroll
        for (int kc = 0; kc < 2; ++kc) {
            half8_t af[4], bf[4];
#pragma unroll
            for (int mt = 0; mt < 4; ++mt)
                af[mt] = *(const half8_t*)&As[(wm + mt * 16 + lc) * 64 + kc * 32 + lq * 8];
#pragma unroll
            for (int nt = 0; nt < 4; ++nt)
                bf[nt] = *(const half8_t*)&Bs[(wn + nt * 16 + lc) * 64 + kc * 32 + lq * 8];
#pragma unroll
            for (int mt = 0; mt < 4; ++mt)
#pragma unroll
                for (int nt = 0; nt < 4; ++nt)
                    acc[mt][nt] = __builtin_amdgcn_mfma_f32_16x16x32_f16(af[mt], bf[nt],
                                                                         acc[mt][nt], 0, 0, 0);
        }
    }
#pragma unroll
    for (int nt = 0; nt < 4; ++nt) {
        const int col = bn + wn + nt * 16 + lc;
        const float bv = bias[col];
        float s = 0.0f, q = 0.0f;
#pragma unroll
        for (int mt = 0; mt < 4; ++mt) {
#pragma unroll
            for (int v = 0; v < 4; ++v) {
                const int row = bm + wm + mt * 16 + lq * 4 + v;
                float val = acc[mt][nt][v] + bv;
                if (RELU) val = fmaxf(val, 0.0f);
                C[(size_t)row * N + col] = val;
                if (STATS) { s += val; q += val * val; }
            }
        }
        if (STATS) {
            s += __shfl_xor(s, 16); s += __shfl_xor(s, 32);
            q += __shfl_xor(q, 16); q += __shfl_xor(q, 32);
            if (lq == 0) {
                atomicAdd(&psum[col], s);
                atomicAdd(&psq[col], q);
            }
        }
    }
}

// ---------------- standalone GEMM (fallback path) ----------------
template <bool RELU, bool STATS>
__global__ __launch_bounds__(256) void gemm_f16(const _Float16* __restrict__ A,
                                                const _Float16* __restrict__ B,
                                                const float* __restrict__ bias,
                                                float* __restrict__ C,
                                                int N, int K,
                                                float* __restrict__ psum,
                                                float* __restrict__ psq) {
    __shared__ _Float16 As[128 * 64];
    __shared__ _Float16 Bs[128 * 64];
    gemm_body<RELU, STATS>(A, B, bias, C, N, K, psum, psq, As, Bs,
                           blockIdx.y * 128, blockIdx.x * 128, threadIdx.x);
}

// ---------------- standalone bnorm (fallback path) ----------------
__global__ __launch_bounds__(256) void bnorm_relu_f16(const float4* __restrict__ y,
                                                      const float* __restrict__ psum,
                                                      const float* __restrict__ psq,
                                                      const float* __restrict__ g,
                                                      const float* __restrict__ be,
                                                      _Float16* __restrict__ xt) {
    size_t i = (size_t)blockIdx.x * 256 + threadIdx.x;
    int c0 = (int)((i * 4) & (CH - 1));
    float4 v = y[i];
    union { uint2 w; _Float16 h[4]; } o;
    float vv[4] = {v.x, v.y, v.z, v.w};
#pragma unroll
    for (int k = 0; k < 4; ++k) {
        int c = c0 + k;
        float mean = psum[c] * (1.0f / 16384.0f);
        float var  = psq[c] * (1.0f / 16384.0f) - mean * mean;
        float rstd = 1.0f / sqrtf(var + 1e-5f);
        float t = ((vv[k] - mean) * rstd) * g[c] + be[c];
        o.h[k] = (_Float16)fmaxf(t, 0.0f);
    }
    *(uint2*)((_Float16*)xt + i * 4) = o.w;
}

// ---------------- standalone head2 (fallback path) ----------------
__global__ __launch_bounds__(256) void head2_kernel(const float* __restrict__ h,
                                                    const float* __restrict__ Wc2,
                                                    const float* __restrict__ bc2,
                                                    float* __restrict__ out) {
    const int wave = threadIdx.x >> 6, lane = threadIdx.x & 63;
    const int p = blockIdx.x * 4 + wave;
    const float* hp = h + (size_t)p * 256;
    float acc[5] = {0.f, 0.f, 0.f, 0.f, 0.f};
#pragma unroll
    for (int fo = 0; fo < 4; ++fo) {
        int f = lane + fo * 64;
        float hv = hp[f];
#pragma unroll
        for (int j = 0; j < 5; ++j) acc[j] += hv * Wc2[j * 256 + f];
    }
#pragma unroll
    for (int j = 0; j < 5; ++j)
#pragma unroll
        for (int off = 32; off; off >>= 1) acc[j] += __shfl_down(acc[j], off);
    if (lane == 0) {
#pragma unroll
        for (int j = 0; j < 5; ++j) out[(size_t)p * 5 + j] = acc[j] + bc2[j];
    }
}

// ---------------- persistent cooperative pipeline (512 blocks, 2/CU margin) ----------------
// Fences: release (__threadfence) BEFORE grid.sync flushes dirty L2 (buffer_wbl2);
// acquire (__threadfence) AFTER grid.sync invalidates stale L2 (buffer_inv) — G16:
// per-XCD L2s are not coherent, kernel-internal phase handoff needs both sides.
#define PHASE_SYNC() do { __threadfence(); grid.sync(); __threadfence(); } while (0)

__global__ __launch_bounds__(256, 2) void pipe_kernel(
    const _Float16* __restrict__ xtA, _Float16* __restrict__ xtB,
    _Float16* __restrict__ feat16, float* __restrict__ y,
    const _Float16* __restrict__ w0, const _Float16* __restrict__ w1,
    const _Float16* __restrict__ w2, const _Float16* __restrict__ wc1,
    const float* __restrict__ bb0, const float* __restrict__ bb1, const float* __restrict__ bb2,
    const float* __restrict__ gg0, const float* __restrict__ gg1, const float* __restrict__ gg2,
    const float* __restrict__ be0, const float* __restrict__ be1, const float* __restrict__ be2,
    const int* __restrict__ idx, float* __restrict__ ps,
    const float* __restrict__ bc1p, const float* __restrict__ Wc2p,
    const float* __restrict__ bc2p, float* __restrict__ outp) {
    cg::grid_group grid = cg::this_grid();
    __shared__ _Float16 As[128 * 64];
    __shared__ _Float16 Bs[128 * 64];
    const int bid = blockIdx.x;
    const int tid = threadIdx.x;

    const _Float16* wts[3] = {w0, w1, w2};
    const float* bbs[3] = {bb0, bb1, bb2};
    const float* ggs[3] = {gg0, gg1, gg2};
    const float* bes[3] = {be0, be1, be2};
    const _Float16* cur = xtA;
    _Float16* nxt = xtB;

    for (int blk = 0; blk < 3; ++blk) {
        // ---- feat phase: 4096 virtual blocks, 8 per real block; batch = f(bid&7) const ----
        if (bid == 0) {
            float4 z = {0.f, 0.f, 0.f, 0.f};
            ((float4*)ps)[tid] = z;   // zero psum||psq (1024 floats)
        }
        {
            const int batch = (bid & 7) >> 1;     // 512 % 8 == 0 -> constant over s
            const int halfp = bid & 1;
            const int wave  = tid >> 6;
            const int ch0   = (tid & 63) * 8;
            const int base  = batch * NPTS;
            for (int s = 0; s < 8; ++s) {
                const int vb = bid + s * 512;
                const int p  = base + halfp * 2048 + ((vb >> 3) << 2) + wave;
                feat_body(cur, idx, feat16, p, base, ch0);
            }
        }
        PHASE_SYNC();
        // ---- gemm phase: 512 tiles, one per block (same parallelism as standalone) ----
        gemm_body<false, true>(feat16, wts[blk], bbs[blk], y, CH, 2 * CH,
                               ps, ps + CH, As, Bs,
                               (bid >> 2) * 128, (bid & 3) * 128, tid);
        PHASE_SYNC();
        // ---- bnorm phase: 8192 virtual blocks, 16 per real block ----
        for (int s = 0; s < 16; ++s) {
            size_t i = (size_t)(bid + s * 512) * 256 + tid;
            int c0 = (int)((i * 4) & (CH - 1));
            float4 v = ((const float4*)y)[i];
            union { uint2 w; _Float16 h[4]; } o;
            float vv[4] = {v.x, v.y, v.z, v.w};
#pragma unroll
            for (int k = 0; k < 4; ++k) {
                int c = c0 + k;
                float mean = ps[c] * (1.0f / 16384.0f);
                float var  = ps[CH + c] * (1.0f / 16384.0f) - mean * mean;
                float rstd = 1.0f / sqrtf(var + 1e-5f);
                float t = ((vv[k] - mean) * rstd) * ggs[blk][c] + bes[blk][c];
                o.h[k] = (_Float16)fmaxf(t, 0.0f);
            }
            *(uint2*)(nxt + i * 4) = o.w;
        }
        PHASE_SYNC();
        const _Float16* t = cur; cur = nxt; nxt = (_Float16*)t;
    }
    // ---- head gemm: 256 tiles ----
    if (bid < 256)
        gemm_body<true, false>(cur, wc1, bc1p, y, 256, CH, nullptr, nullptr,
                               As, Bs, (bid >> 1) * 128, (bid & 1) * 128, tid);
    PHASE_SYNC();
    // ---- head2: 4096 virtual blocks, 8 per real block ----
    {
        const int wave = tid >> 6, lane = tid & 63;
        for (int s = 0; s < 8; ++s) {
            const int p = (bid + s * 512) * 4 + wave;
            const float* hp = y + (size_t)p * 256;
            float a5[5] = {0.f, 0.f, 0.f, 0.f, 0.f};
#pragma unroll
            for (int fo = 0; fo < 4; ++fo) {
                int f = lane + fo * 64;
                float hv = hp[f];
#pragma unroll
                for (int j = 0; j < 5; ++j) a5[j] += hv * Wc2p[j * 256 + f];
            }
#pragma unroll
            for (int j = 0; j < 5; ++j)
#pragma unroll
                for (int off = 32; off; off >>= 1) a5[j] += __shfl_down(a5[j], off);
            if (lane == 0) {
#pragma unroll
                for (int j = 0; j < 5; ++j) outp[(size_t)p * 5 + j] = a5[j] + bc2p[j];
            }
        }
    }
}

extern "C" void kernel_launch(void* const* d_in, const int* in_sizes, int n_in,
                              void* d_out, int out_size, void* d_ws, size_t ws_size,
                              hipStream_t stream) {
    const float* x   = (const float*)d_in[0];
    const float* pos = (const float*)d_in[1];
    const float* W[3]  = {(const float*)d_in[2], (const float*)d_in[6], (const float*)d_in[10]};
    const float* bb[3] = {(const float*)d_in[3], (const float*)d_in[7], (const float*)d_in[11]};
    const float* gg[3] = {(const float*)d_in[4], (const float*)d_in[8], (const float*)d_in[12]};
    const float* be[3] = {(const float*)d_in[5], (const float*)d_in[9], (const float*)d_in[13]};
    const float* Wc1 = (const float*)d_in[14];
    const float* bc1 = (const float*)d_in[15];
    const float* Wc2 = (const float*)d_in[16];
    const float* bc2 = (const float*)d_in[17];
    float* out = (float*)d_out;

    const size_t MB = 1ull << 20;
    char* ws = (char*)d_ws;
    _Float16* xtA16  = (_Float16*)(ws);                  // 16 MB
    _Float16* xtB16  = (_Float16*)(ws + 16 * MB);        // 16 MB
    _Float16* feat16 = (_Float16*)(ws + 32 * MB);        // 32 MB
    float*    y      = (float*)   (ws + 64 * MB);        // 32 MB
    _Float16* w16[3] = {(_Float16*)(ws + 96 * MB), (_Float16*)(ws + 97 * MB),
                        (_Float16*)(ws + 98 * MB)};      // 1 MB each
    _Float16* wc116  = (_Float16*)(ws + 99 * MB);        // 256 KB
    int*      idxB   = (int*)     (ws + 100 * MB);       // 320 KB
    float*    psum   = (float*)   (ws + 101 * MB);       // 4 KB (psum||psq)
    float*    psq    = psum + CH;

    prep_kernel<<<dim3(8192 + 1664), 256, 0, stream>>>(x, xtA16, W[0], W[1], W[2], Wc1,
                                                       w16[0], w16[1], w16[2], wc116);
    knn_kernel<<<dim3(NB * 64), 1024, 0, stream>>>(pos, idxB);

    void* kargs[] = {
        (void*)&xtA16, (void*)&xtB16, (void*)&feat16, (void*)&y,
        (void*)&w16[0], (void*)&w16[1], (void*)&w16[2], (void*)&wc116,
        (void*)&bb[0], (void*)&bb[1], (void*)&bb[2],
        (void*)&gg[0], (void*)&gg[1], (void*)&gg[2],
        (void*)&be[0], (void*)&be[1], (void*)&be[2],
        (void*)&idxB, (void*)&psum,
        (void*)&bc1, (void*)&Wc2, (void*)&bc2, (void*)&out};
    hipError_t err = hipLaunchCooperativeKernel((const void*)pipe_kernel, dim3(512),
                                                dim3(256), kargs, 0, stream);
    if (err != hipSuccess) {
        // fallback: r9 multi-dispatch sequence (known-good 361 us)
        _Float16* cur = xtA16;
        _Float16* nxt = xtB16;
        for (int blk = 0; blk < 3; ++blk) {
            feat_kernel<<<dim3(TOT / 4), 256, 0, stream>>>(cur, idxB, feat16, psum);
            gemm_f16<false, true><<<dim3(CH / 128, TOT / 128), 256, 0, stream>>>(
                feat16, w16[blk], bb[blk], y, CH, 2 * CH, psum, psq);
            bnorm_relu_f16<<<dim3((size_t)TOT * CH / 4 / 256), 256, 0, stream>>>(
                (const float4*)y, psum, psq, gg[blk], be[blk], nxt);
            _Float16* t = cur; cur = nxt; nxt = t;
        }
        float* h = y;
        gemm_f16<true, false><<<dim3(256 / 128, TOT / 128), 256, 0, stream>>>(
            cur, wc116, bc1, h, 256, CH, nullptr, nullptr);
        head2_kernel<<<dim3(TOT / 4), 256, 0, stream>>>(h, Wc2, bc2, out);
    }
}

// Round 13
// 360.806 us; speedup vs baseline: 5.0533x; 5.0533x over previous
//
#include <hip/hip_runtime.h>

#define NPTS 4096
#define NB   4
#define CH   512
#define TOT  (NB * NPTS)   // 16384
#define KNN  5

typedef _Float16 half8_t __attribute__((ext_vector_type(8)));
typedef float    f32x4   __attribute__((ext_vector_type(4)));

typedef __attribute__((address_space(1))) const void gas_t;
typedef __attribute__((address_space(3))) void las_t;
#define GLOAD16(g, l) __builtin_amdgcn_global_load_lds((gas_t*)(g), (las_t*)(l), 16, 0, 0)

// ---------------- prep: transpose (blocks 0..8191) + weight convert (8192..9855) ----------------
__global__ __launch_bounds__(256) void prep_kernel(const float* __restrict__ x,
                                                   _Float16* __restrict__ xt,
                                                   const float* __restrict__ s0,
                                                   const float* __restrict__ s1,
                                                   const float* __restrict__ s2,
                                                   const float* __restrict__ s3,
                                                   _Float16* __restrict__ d0,
                                                   _Float16* __restrict__ d1,
                                                   _Float16* __restrict__ d2,
                                                   _Float16* __restrict__ d3) {
    __shared__ float tile[32][33];
    const int blk = blockIdx.x;
    if (blk < 8192) {
        int b  = blk >> 11;
        int by = (blk >> 7) & 15;
        int bx = blk & 127;
        int n0 = bx * 32, c0 = by * 32;
        int tx = threadIdx.x & 31, ty = threadIdx.x >> 5;
        const float* xp = x + ((size_t)b * CH + c0) * NPTS + n0;
#pragma unroll
        for (int i = 0; i < 32; i += 8)
            tile[ty + i][tx] = xp[(size_t)(ty + i) * NPTS + tx];   // tile[chan][n]
        __syncthreads();
        int t2 = threadIdx.x & 15, rr = threadIdx.x >> 4;
#pragma unroll
        for (int i = 0; i < 32; i += 16) {
            int nn = rr + i;
            union { unsigned u; _Float16 h[2]; } o;
            o.h[0] = (_Float16)tile[2 * t2][nn];
            o.h[1] = (_Float16)tile[2 * t2 + 1][nn];
            *(unsigned*)(xt + ((size_t)b * NPTS + n0 + nn) * CH + c0 + 2 * t2) = o.u;
        }
    } else {
        const int cb = blk - 8192;   // 0..1663
        const float* s; _Float16* d; int i;
        if (cb < 512)       { s = s0; d = d0; i = cb; }
        else if (cb < 1024) { s = s1; d = d1; i = cb - 512; }
        else if (cb < 1536) { s = s2; d = d2; i = cb - 1024; }
        else                { s = s3; d = d3; i = cb - 1536; }
        int q = i * 256 + threadIdx.x;
        float4 v = ((const float4*)s)[q];
        union { unsigned long long u; _Float16 h[4]; } o;
        o.h[0] = (_Float16)v.x; o.h[1] = (_Float16)v.y;
        o.h[2] = (_Float16)v.z; o.h[3] = (_Float16)v.w;
        *(unsigned long long*)(d + (size_t)q * 4) = o.u;
    }
}

// ---------------- KNN: FROZEN at v2 (verified bit-exact): 16 waves, scalar LDS reads ----------------
__global__ __launch_bounds__(1024) void knn_kernel(const float* __restrict__ pos,
                                                   int* __restrict__ idxOut) {
#pragma clang fp contract(off)
    __shared__ float cx[NPTS];
    __shared__ float cy[NPTS];
    __shared__ float d2s[NPTS];
    __shared__ float cd[16][64][KNN];
    __shared__ int   ci[16][64][KNN];
    __shared__ float cd2[4][64][KNN];
    __shared__ int   ci2[4][64][KNN];
    const int b  = blockIdx.x >> 6;
    const int q0 = (blockIdx.x & 63) << 6;
    const int wv = threadIdx.x >> 6;
    const int ln = threadIdx.x & 63;
    const int n  = q0 + ln;
    const float2* P = (const float2*)(pos + (size_t)b * NPTS * 2);
    for (int m = threadIdx.x; m < NPTS; m += 1024) {
        float2 c = P[m];
        cx[m] = c.x; cy[m] = c.y;
        float xx = c.x * c.x;
        float yy = c.y * c.y;
        d2s[m] = xx + yy;
    }
    __syncthreads();
    const float xq = cx[n], yq = cy[n], d2q = d2s[n];
    float bd0 = 3.4e38f, bd1 = 3.4e38f, bd2 = 3.4e38f, bd3 = 3.4e38f, bd4 = 3.4e38f;
    int   bi0 = 0, bi1 = 0, bi2 = 0, bi3 = 0, bi4 = 0;
    const int m0 = wv << 8, m1 = m0 + 256;
    for (int m = m0; m < m1; m += 4) {
        float dist[4];
#pragma unroll
        for (int u = 0; u < 4; ++u) {
            float px  = xq * cx[m + u];
            float dot = __builtin_fmaf(yq, cy[m + u], px);
            float s   = d2q + d2s[m + u];
            float t2  = 2.0f * dot;
            dist[u] = s - t2;
        }
        float mn = fminf(fminf(dist[0], dist[1]), fminf(dist[2], dist[3]));
        if (mn < bd4) {
#pragma unroll
            for (int u = 0; u < 4; ++u) {
                float d = dist[u];
                if (d < bd4) {
                    bd4 = d; bi4 = m + u;
                    if (bd4 < bd3) { float t = bd3; bd3 = bd4; bd4 = t; int v = bi3; bi3 = bi4; bi4 = v; }
                    if (bd3 < bd2) { float t = bd2; bd2 = bd3; bd3 = t; int v = bi2; bi2 = bi3; bi3 = v; }
                    if (bd2 < bd1) { float t = bd1; bd1 = bd2; bd2 = t; int v = bi1; bi1 = bi2; bi2 = v; }
                    if (bd1 < bd0) { float t = bd0; bd0 = bd1; bd1 = t; int v = bi0; bi0 = bi1; bi1 = v; }
                }
            }
        }
    }
    cd[wv][ln][0] = bd0; cd[wv][ln][1] = bd1; cd[wv][ln][2] = bd2; cd[wv][ln][3] = bd3; cd[wv][ln][4] = bd4;
    ci[wv][ln][0] = bi0; ci[wv][ln][1] = bi1; ci[wv][ln][2] = bi2; ci[wv][ln][3] = bi3; ci[wv][ln][4] = bi4;
    __syncthreads();
    // stage A: waves 0..3 each merge 4 consecutive wave-lists (ascending w keeps tie order)
    if (wv < 4) {
        float md0 = 3.4e38f, md1 = 3.4e38f, md2 = 3.4e38f, md3 = 3.4e38f, md4 = 3.4e38f;
        int   mi0 = 0, mi1 = 0, mi2 = 0, mi3 = 0, mi4 = 0;
#pragma unroll
        for (int w = 4 * wv; w < 4 * wv + 4; ++w) {
#pragma unroll
            for (int j = 0; j < KNN; ++j) {
                float d = cd[w][ln][j];
                int  id = ci[w][ln][j];
                if (d < md4) {
                    md4 = d; mi4 = id;
                    if (md4 < md3) { float t = md3; md3 = md4; md4 = t; int v = mi3; mi3 = mi4; mi4 = v; }
                    if (md3 < md2) { float t = md2; md2 = md3; md3 = t; int v = mi2; mi2 = mi3; mi3 = v; }
                    if (md2 < md1) { float t = md1; md1 = md2; md2 = t; int v = mi1; mi1 = mi2; mi2 = v; }
                    if (md1 < md0) { float t = md0; md0 = md1; md1 = t; int v = mi0; mi0 = mi1; mi1 = v; }
                }
            }
        }
        cd2[wv][ln][0] = md0; cd2[wv][ln][1] = md1; cd2[wv][ln][2] = md2; cd2[wv][ln][3] = md3; cd2[wv][ln][4] = md4;
        ci2[wv][ln][0] = mi0; ci2[wv][ln][1] = mi1; ci2[wv][ln][2] = mi2; ci2[wv][ln][3] = mi3; ci2[wv][ln][4] = mi4;
    }
    __syncthreads();
    // stage B: wave 0 merges the 4 group-lists (ascending group order)
    if (wv == 0) {
        float md0 = 3.4e38f, md1 = 3.4e38f, md2 = 3.4e38f, md3 = 3.4e38f, md4 = 3.4e38f;
        int   mi0 = 0, mi1 = 0, mi2 = 0, mi3 = 0, mi4 = 0;
#pragma unroll
        for (int w = 0; w < 4; ++w) {
#pragma unroll
            for (int j = 0; j < KNN; ++j) {
                float d = cd2[w][ln][j];
                int  id = ci2[w][ln][j];
                if (d < md4) {
                    md4 = d; mi4 = id;
                    if (md4 < md3) { float t = md3; md3 = md4; md4 = t; int v = mi3; mi3 = mi4; mi4 = v; }
                    if (md3 < md2) { float t = md2; md2 = md3; md3 = t; int v = mi2; mi2 = mi3; mi3 = v; }
                    if (md2 < md1) { float t = md1; md1 = md2; md2 = t; int v = mi1; mi1 = mi2; mi2 = v; }
                    if (md1 < md0) { float t = md0; md0 = md1; md1 = t; int v = mi0; mi0 = mi1; mi1 = v; }
                }
            }
        }
        int* op = idxOut + ((size_t)b * NPTS + n) * KNN;
        op[0] = mi0; op[1] = mi1; op[2] = mi2; op[3] = mi3; op[4] = mi4;
    }
}

// ---------------- feat build: xt16 -> feat16 [TOT, 2CH] interleaved ----------------
// 8 ch/thread, 16B ops. XCD-swizzled point mapping (r7: +8us, L2-resident gather).
__global__ __launch_bounds__(256) void feat_kernel(const _Float16* __restrict__ xt,
                                                   const int* __restrict__ idx,
                                                   _Float16* __restrict__ feat,
                                                   float* __restrict__ pzero) {
    if (blockIdx.x == 0) {
        float4 z = {0.f, 0.f, 0.f, 0.f};
        ((float4*)pzero)[threadIdx.x] = z;   // 256*16B = 4KB = 2*CH floats
    }
    const int blk   = blockIdx.x;           // 4096 blocks
    const int batch = (blk & 7) >> 1;
    const int halfp = blk & 1;
    const int j     = blk >> 3;             // 0..511
    const int p     = batch * NPTS + halfp * 2048 + j * 4 + (threadIdx.x >> 6);
    const int base  = batch * NPTS;
    const int* ip   = idx + (size_t)p * KNN;
    const int ch0   = (threadIdx.x & 63) * 8;
    const _Float16* xr = xt + (size_t)p * CH + ch0;
    const _Float16* g0 = xt + (size_t)(base + ip[0]) * CH + ch0;
    const _Float16* g1 = xt + (size_t)(base + ip[1]) * CH + ch0;
    const _Float16* g2 = xt + (size_t)(base + ip[2]) * CH + ch0;
    const _Float16* g3 = xt + (size_t)(base + ip[3]) * CH + ch0;
    const _Float16* g4 = xt + (size_t)(base + ip[4]) * CH + ch0;
    union u16x8 { uint4 v; _Float16 h[8]; };
    u16x8 ux, u0, u1, u2, u3, u4;
    ux.v = *(const uint4*)xr;
    u0.v = *(const uint4*)g0;
    u1.v = *(const uint4*)g1;
    u2.v = *(const uint4*)g2;
    u3.v = *(const uint4*)g3;
    u4.v = *(const uint4*)g4;
    u16x8 oa, ob;
#pragma unroll
    for (int j2 = 0; j2 < 8; ++j2) {
        float xv = (float)ux.h[j2];
        float mr = fmaxf(fmaxf(fmaxf((float)u0.h[j2], (float)u1.h[j2]),
                               fmaxf((float)u2.h[j2], (float)u3.h[j2])), (float)u4.h[j2]) - xv;
        if (j2 < 4) {
            oa.h[2 * j2]     = ux.h[j2];
            oa.h[2 * j2 + 1] = (_Float16)mr;
        } else {
            ob.h[2 * (j2 - 4)]     = ux.h[j2];
            ob.h[2 * (j2 - 4) + 1] = (_Float16)mr;
        }
    }
    _Float16* op = feat + (size_t)p * 2 * CH + 2 * ch0;
    *(uint4*)(op)     = oa.v;
    *(uint4*)(op + 8) = ob.v;
}

// ---------------- f16 MFMA GEMM: C[M,N] = A[M,K] @ B[N,K]^T + bias ----------------
// 128x128 tile, BK=64 (32KB LDS -> 5 blocks/CU; BK=128 regressed: m132 mechanism),
// 4 waves (2x2), 16x16x32 MFMA, global_load_lds width=16 into LINEAR LDS [128][64].
template <bool RELU, bool STATS>
__global__ __launch_bounds__(256) void gemm_f16(const _Float16* __restrict__ A,
                                                const _Float16* __restrict__ B,
                                                const float* __restrict__ bias,
                                                float* __restrict__ C,
                                                int N, int K,
                                                float* __restrict__ psum,
                                                float* __restrict__ psq) {
    __shared__ _Float16 As[128 * 64];   // 16 KB, row-major [row][kk]
    __shared__ _Float16 Bs[128 * 64];   // 16 KB
    const int tid = threadIdx.x;
    const int bm = blockIdx.y * 128;
    const int bn = blockIdx.x * 128;
    const int wv = tid >> 6, ln = tid & 63;
    const int wm = (wv >> 1) * 64, wn = (wv & 1) * 64;
    const int lq = ln >> 4, lc = ln & 15;
    const int srow = wv * 8 + (ln >> 3);
    const int scol = (ln & 7) * 8;
    const _Float16* Ag = A + (size_t)(bm + srow) * K + scol;
    const _Float16* Bg = B + (size_t)(bn + srow) * K + scol;
    _Float16* AsW = As + wv * 512;   // wave-uniform LDS base (+ c*2048 per chunk)
    _Float16* BsW = Bs + wv * 512;

    f32x4 zero = {0.0f, 0.0f, 0.0f, 0.0f};
    f32x4 acc[4][4];
#pragma unroll
    for (int i = 0; i < 4; ++i)
#pragma unroll
        for (int j = 0; j < 4; ++j) acc[i][j] = zero;

    for (int k0 = 0; k0 < K; k0 += 64) {
        __syncthreads();                 // WAR: all waves done reading previous tile
#pragma unroll
        for (int c = 0; c < 4; ++c) {
            GLOAD16(Ag + (size_t)c * 32 * K + k0, AsW + c * 2048);
            GLOAD16(Bg + (size_t)c * 32 * K + k0, BsW + c * 2048);
        }
        __syncthreads();                 // drains vmcnt(0): tile ready
#pragma unroll
        for (int kc = 0; kc < 2; ++kc) {
            half8_t af[4], bf[4];
#pragma unroll
            for (int mt = 0; mt < 4; ++mt)
                af[mt] = *(const half8_t*)&As[(wm + mt * 16 + lc) * 64 + kc * 32 + lq * 8];
#pragma unroll
            for (int nt = 0; nt < 4; ++nt)
                bf[nt] = *(const half8_t*)&Bs[(wn + nt * 16 + lc) * 64 + kc * 32 + lq * 8];
#pragma unroll
            for (int mt = 0; mt < 4; ++mt)
#pragma unroll
                for (int nt = 0; nt < 4; ++nt)
                    acc[mt][nt] = __builtin_amdgcn_mfma_f32_16x16x32_f16(af[mt], bf[nt],
                                                                         acc[mt][nt], 0, 0, 0);
        }
    }
    // epilogue: C/D layout col=lane&15, row=quad*4+reg
#pragma unroll
    for (int nt = 0; nt < 4; ++nt) {
        const int col = bn + wn + nt * 16 + lc;
        const float bv = bias[col];
        float s = 0.0f, q = 0.0f;
#pragma unroll
        for (int mt = 0; mt < 4; ++mt) {
#pragma unroll
            for (int v = 0; v < 4; ++v) {
                const int row = bm + wm + mt * 16 + lq * 4 + v;
                float val = acc[mt][nt][v] + bv;
                if (RELU) val = fmaxf(val, 0.0f);
                C[(size_t)row * N + col] = val;
                if (STATS) { s += val; q += val * val; }
            }
        }
        if (STATS) {
            s += __shfl_xor(s, 16); s += __shfl_xor(s, 32);
            q += __shfl_xor(q, 16); q += __shfl_xor(q, 32);
            if (lq == 0) {
                atomicAdd(&psum[col], s);
                atomicAdd(&psq[col], q);
            }
        }
    }
}

// ---------------- y(f32) -> relu(bnorm) -> xt16 (f16); stats finalize fused in ----------------
__global__ __launch_bounds__(256) void bnorm_relu_f16(const float4* __restrict__ y,
                                                      const float* __restrict__ psum,
                                                      const float* __restrict__ psq,
                                                      const float* __restrict__ g,
                                                      const float* __restrict__ be,
                                                      _Float16* __restrict__ xt) {
    size_t i = (size_t)blockIdx.x * 256 + threadIdx.x;   // over TOT*CH/4
    int c0 = (int)((i * 4) & (CH - 1));
    float4 v = y[i];
    union { uint2 w; _Float16 h[4]; } o;
    float vv[4] = {v.x, v.y, v.z, v.w};
#pragma unroll
    for (int k = 0; k < 4; ++k) {
        int c = c0 + k;
        float mean = psum[c] * (1.0f / 16384.0f);
        float var  = psq[c] * (1.0f / 16384.0f) - mean * mean;
        float rstd = 1.0f / sqrtf(var + 1e-5f);
        float t = ((vv[k] - mean) * rstd) * g[c] + be[c];
        o.h[k] = (_Float16)fmaxf(t, 0.0f);
    }
    *(uint2*)((_Float16*)xt + i * 4) = o.w;
}

// ---------------- head stage 2 (shuffle) ----------------
__global__ __launch_bounds__(256) void head2_kernel(const float* __restrict__ h,
                                                    const float* __restrict__ Wc2,
                                                    const float* __restrict__ bc2,
                                                    float* __restrict__ out) {
    const int wave = threadIdx.x >> 6, lane = threadIdx.x & 63;
    const int p = blockIdx.x * 4 + wave;
    const float* hp = h + (size_t)p * 256;
    float acc[5] = {0.f, 0.f, 0.f, 0.f, 0.f};
#pragma unroll
    for (int fo = 0; fo < 4; ++fo) {
        int f = lane + fo * 64;
        float hv = hp[f];
#pragma unroll
        for (int j = 0; j < 5; ++j) acc[j] += hv * Wc2[j * 256 + f];
    }
#pragma unroll
    for (int j = 0; j < 5; ++j)
#pragma unroll
        for (int off = 32; off; off >>= 1) acc[j] += __shfl_down(acc[j], off);
    if (lane == 0) {
#pragma unroll
        for (int j = 0; j < 5; ++j) out[(size_t)p * 5 + j] = acc[j] + bc2[j];
    }
}

extern "C" void kernel_launch(void* const* d_in, const int* in_sizes, int n_in,
                              void* d_out, int out_size, void* d_ws, size_t ws_size,
                              hipStream_t stream) {
    const float* x   = (const float*)d_in[0];
    const float* pos = (const float*)d_in[1];
    const float* W[3]  = {(const float*)d_in[2], (const float*)d_in[6], (const float*)d_in[10]};
    const float* bb[3] = {(const float*)d_in[3], (const float*)d_in[7], (const float*)d_in[11]};
    const float* gg[3] = {(const float*)d_in[4], (const float*)d_in[8], (const float*)d_in[12]};
    const float* be[3] = {(const float*)d_in[5], (const float*)d_in[9], (const float*)d_in[13]};
    const float* Wc1 = (const float*)d_in[14];
    const float* bc1 = (const float*)d_in[15];
    const float* Wc2 = (const float*)d_in[16];
    const float* bc2 = (const float*)d_in[17];
    float* out = (float*)d_out;

    const size_t MB = 1ull << 20;
    char* ws = (char*)d_ws;
    _Float16* xtA16  = (_Float16*)(ws);                  // 16 MB
    _Float16* xtB16  = (_Float16*)(ws + 16 * MB);        // 16 MB
    _Float16* feat16 = (_Float16*)(ws + 32 * MB);        // 32 MB
    float*    y      = (float*)   (ws + 64 * MB);        // 32 MB (reused as h at head)
    _Float16* w16[3] = {(_Float16*)(ws + 96 * MB), (_Float16*)(ws + 97 * MB),
                        (_Float16*)(ws + 98 * MB)};      // 1 MB each
    _Float16* wc116  = (_Float16*)(ws + 99 * MB);        // 256 KB
    int*      idxB   = (int*)     (ws + 100 * MB);       // 320 KB
    float*    psum   = (float*)   (ws + 101 * MB);       // 4 KB (psum||psq)
    float*    psq    = psum + CH;

    prep_kernel<<<dim3(8192 + 1664), 256, 0, stream>>>(x, xtA16, W[0], W[1], W[2], Wc1,
                                                       w16[0], w16[1], w16[2], wc116);
    knn_kernel<<<dim3(NB * 64), 1024, 0, stream>>>(pos, idxB);

    _Float16* cur = xtA16;
    _Float16* nxt = xtB16;
    for (int blk = 0; blk < 3; ++blk) {
        feat_kernel<<<dim3(TOT / 4), 256, 0, stream>>>(cur, idxB, feat16, psum);
        gemm_f16<false, true><<<dim3(CH / 128, TOT / 128), 256, 0, stream>>>(
            feat16, w16[blk], bb[blk], y, CH, 2 * CH, psum, psq);
        bnorm_relu_f16<<<dim3((size_t)TOT * CH / 4 / 256), 256, 0, stream>>>(
            (const float4*)y, psum, psq, gg[blk], be[blk], nxt);
        _Float16* t = cur; cur = nxt; nxt = t;
    }
    float* h = y;   // y free after last bnorm
    gemm_f16<true, false><<<dim3(256 / 128, TOT / 128), 256, 0, stream>>>(
        cur, wc116, bc1, h, 256, CH, nullptr, nullptr);
    head2_kernel<<<dim3(TOT / 4), 256, 0, stream>>>(h, Wc2, bc2, out);
}